// Round 5
// baseline (474.769 us; speedup 1.0000x reference)
//
#include <hip/hip_runtime.h>

using half8   = __attribute__((ext_vector_type(8))) _Float16;
using floatx4 = __attribute__((ext_vector_type(4))) float;

namespace {
constexpr int S = 196, D = 512, C = 1006;
constexpr int CB   = 16;    // block c-tile
constexpr int EBLK = 256;   // block e-tile (et split; known 2x tanh cost, keeps regs sane)
constexpr int BK   = 64;    // k-chunk (8 chunks, 2 MFMA k-steps each)
constexpr int TPB  = 512;   // 8 waves = 4 e-slots x 2 s-groups; grid 256 = 1 block/CU
constexpr int RS   = 64;    // Tc row stride (halfs); 16B-seg XOR swizzle (LDS only)
constexpr float KTANH = 2.885390082f;    // 2/ln2 folded into img staging
constexpr float INVK  = 0.34657359028f;  // ln2/2 to recover raw img
constexpr float LOG2E = 1.44269504f;     // folded into W at prep: acc = log2e*feat

// r9: W is NOT staged in LDS. bf frags are read straight from a plain row-major
// f16 W image in ws (512 KB, L2-resident; each 4-lane quad reads one aligned
// 64B line -> 16 full lines per instr). r8 profiling showed the LDS pipe at
// ~55% busy/chunk (176 b128 ops); W staging was 64 reads + 32KB of DMA writes
// of that with ZERO reuse (each bf byte consumed by exactly one wave).

// swizzled offset for Tc (halfs): row stride 64, 16B-seg XOR'd by row&7
__device__ __forceinline__ int sw_off(int row, int seg) {
    return row * RS + ((seg ^ (row & 7)) << 3);
}

__device__ __forceinline__ _Float16 tanh_ps(float y) {
    // y = (2/ln2)*x; tanh(x) = 1 - 2/(exp2(y)+1); saturates correctly
    float e = __builtin_amdgcn_exp2f(y);
    return (_Float16)(1.0f - 2.0f * __builtin_amdgcn_rcpf(e + 1.0f));
}

__device__ __forceinline__ half8 tanh8(floatx4 i0, floatx4 i1, floatx4 w0, floatx4 w1) {
    half8 t;
    t[0] = tanh_ps(i0[0] * w0[0]); t[1] = tanh_ps(i0[1] * w0[1]);
    t[2] = tanh_ps(i0[2] * w0[2]); t[3] = tanh_ps(i0[3] * w0[3]);
    t[4] = tanh_ps(i1[0] * w1[0]); t[5] = tanh_ps(i1[1] * w1[1]);
    t[6] = tanh_ps(i1[2] * w1[2]); t[7] = tanh_ps(i1[3] * w1[3]);
    return t;
}

// fc3_w * log2e -> plain row-major f16 image [e:512][k:512] (no swizzle:
// global reads don't bank-conflict; plain rows give aligned 64B-line frags).
__global__ void prep_w16(const float* __restrict__ fw, _Float16* __restrict__ W16) {
    int id = blockIdx.x * blockDim.x + threadIdx.x;    // 32768 half8-segs
    int r  = id >> 6;          // 0..511 (e row)
    int j  = id & 63;          // 0..63  (k seg of 8)
    const float* src = fw + (size_t)r * D + j * 8;
    floatx4 v0 = *(const floatx4*)src;
    floatx4 v1 = *(const floatx4*)(src + 4);
    half8 h;
    h[0] = (_Float16)(v0[0] * LOG2E); h[1] = (_Float16)(v0[1] * LOG2E);
    h[2] = (_Float16)(v0[2] * LOG2E); h[3] = (_Float16)(v0[3] * LOG2E);
    h[4] = (_Float16)(v1[0] * LOG2E); h[5] = (_Float16)(v1[1] * LOG2E);
    h[6] = (_Float16)(v1[2] * LOG2E); h[7] = (_Float16)(v1[3] * LOG2E);
    *(half8*)&W16[(size_t)r * D + j * 8] = h;
}

// One block = (b, 16-c tile, 256-e half) over ALL 196 s-rows: softmax fully local,
// no workspace partials, no atomics (the r5-r7 poison). 8 waves: wv&3 = e-slot,
// wv>>2 = s-group. Tc double-buffered: tanh(chunk k+1) overlaps chunk k's MFMA.
__global__ __launch_bounds__(TPB, 2) void semdec_mfma(
    const float* __restrict__ img, const float* __restrict__ word,
    const _Float16* __restrict__ W16, float* __restrict__ out)
{
    __shared__ __align__(16) _Float16 Tc[2][8 * CB * RS];   // 2 x 16 KB
    __shared__ __align__(16) float imgS[8][D];              // 16 KB, pre-scaled 2/ln2
    __shared__ __align__(16) float red[256 * 33];           // 33 KB, stride-33 (bank-clean)
    // total ~65 KB; 1 block/CU by grid design (256 blocks)

    const int ct = blockIdx.x;           // 0..63
    const int b  = blockIdx.y;           // 0..1
    const int et = blockIdx.z;           // 0..1

    const int tid  = threadIdx.x;
    const int lane = tid & 63;
    const int wv   = tid >> 6;           // 0..7
    const int l15  = lane & 15;
    const int quad = lane >> 4;
    const int sg   = wv >> 2;            // s-group 0/1
    const int ew   = wv & 3;             // e-slot 0..3 (64-wide)

    const int c0 = ct * CB;
    const int e0 = et * EBLK;

    // per-thread W base: row = e0 + ew*64 + l15 (+ej*16), k-byte = quad*8 (+k2*32)
    const _Float16* wbase = W16 + (size_t)(e0 + ew * 64 + l15) * D + quad * 8;

    // T-stage mapping: thread -> (sT2, ciT, segT); s_localT = it*4 + sT2
    const int sT2  = tid >> 7;           // 0..3
    const int ciT  = (tid >> 3) & 15;
    const int segT = tid & 7;
    int cgT = c0 + ciT; if (cgT > C - 1) cgT = C - 1;   // clamp pad rows
    const float* wordRowT = word + (size_t)cgT * D + segT * 8;

    floatx4 lacc[4], aacc[4];            // softmax sums (this sg's s-subset)
    #pragma unroll
    for (int ej = 0; ej < 4; ++ej) {
        lacc[ej] = (floatx4){0.f, 0.f, 0.f, 0.f};
        aacc[ej] = (floatx4){0.f, 0.f, 0.f, 0.f};
    }

    const float* imgB = img + (size_t)b * S * D;
    constexpr int NPASS = 25;            // 24 x 8s + 1 x 4s = 196

    // cyclic word prefetch: wc = chunk for NEXT T compute; wn = one further
    floatx4 wc0 = *(const floatx4*)(wordRowT);
    floatx4 wc1 = *(const floatx4*)(wordRowT + 4);
    floatx4 wn0 = *(const floatx4*)(wordRowT + BK);
    floatx4 wn1 = *(const floatx4*)(wordRowT + BK + 4);

    for (int pr = 0; pr < NPASS; ++pr) {
        const int s0 = pr * 8;
        const int slim = (pr == NPASS - 1) ? 4 : 8;

        __syncthreads();  // prev pass readers of imgS done
        #pragma unroll
        for (int it = 0; it < 2; ++it) {
            int idx = it * TPB + tid;
            int row = idx >> 7, pos = (idx & 127) << 2;
            int srow = s0 + row; if (srow > S - 1) srow = S - 1;  // tail clamp
            floatx4 v = *(const floatx4*)&imgB[(size_t)srow * D + pos];
            floatx4 sv = {v[0] * KTANH, v[1] * KTANH, v[2] * KTANH, v[3] * KTANH};
            *(floatx4*)&imgS[row][pos] = sv;
        }
        __syncthreads();  // imgS visible

        // pass prologue: T(chunk 0) -> Tc[0] (wc holds word chunk 0)
        #pragma unroll
        for (int it = 0; it < 2; ++it) {
            int sl = it * 4 + sT2;
            const float* ip = &imgS[sl][segT * 8];
            floatx4 i0 = *(const floatx4*)ip;
            floatx4 i1 = *(const floatx4*)(ip + 4);
            *(half8*)&Tc[0][sw_off(sl * CB + ciT, segT)] = tanh8(i0, i1, wc0, wc1);
        }
        wc0 = wn0; wc1 = wn1;  // wc <- word chunk 1

        floatx4 acc[4][4];   // [si][ej]; si = this sg's 4 s-rows
        #pragma unroll
        for (int si = 0; si < 4; ++si)
            #pragma unroll
            for (int ej = 0; ej < 4; ++ej)
                acc[si][ej] = (floatx4){0.f, 0.f, 0.f, 0.f};

        for (int kk = 0; kk < 8; ++kk) {
            const int p = kk & 1;
            __syncthreads();  // Tc[p] visible; prev readers of Tc[p^1] done

            // --- bf k2=0: 4 direct global b128 loads (L2-resident W image)
            half8 bf0[4];
            #pragma unroll
            for (int ej = 0; ej < 4; ++ej)
                bf0[ej] = *(const half8*)(wbase + (size_t)ej * 16 * D + kk * BK);

            // --- word prefetch for chunk (kk+2)&7 (cyclic across pass boundary)
            {
                const int kc = ((kk + 2) & 7) * BK;
                wn0 = *(const floatx4*)(wordRowT + kc);
                wn1 = *(const floatx4*)(wordRowT + kc + 4);
            }

            // --- k2=0: af frags + 16 MFMA
            {
                half8 af[4];
                #pragma unroll
                for (int si = 0; si < 4; ++si)
                    af[si] = *(const half8*)&Tc[p][sw_off((sg * 4 + si) * CB + l15, quad)];
                #pragma unroll
                for (int si = 0; si < 4; ++si)
                    #pragma unroll
                    for (int ej = 0; ej < 4; ++ej)
                        acc[si][ej] = __builtin_amdgcn_mfma_f32_16x16x32_f16(
                            af[si], bf0[ej], acc[si][ej], 0, 0, 0);
            }

            // --- bf k2=1 issued early: L2 latency hides under the tanh below
            half8 bf1[4];
            #pragma unroll
            for (int ej = 0; ej < 4; ++ej)
                bf1[ej] = *(const half8*)(wbase + (size_t)ej * 16 * D + kk * BK + 32);

            // --- pipelined T(kk+1) -> Tc[p^1]; VALU/trans overlaps matrix pipe
            if (kk < 7) {
                #pragma unroll
                for (int it = 0; it < 2; ++it) {
                    int sl = it * 4 + sT2;
                    const float* ip = &imgS[sl][((kk + 1) << 6) + segT * 8];
                    floatx4 i0 = *(const floatx4*)ip;
                    floatx4 i1 = *(const floatx4*)(ip + 4);
                    *(half8*)&Tc[p ^ 1][sw_off(sl * CB + ciT, segT)] = tanh8(i0, i1, wc0, wc1);
                }
                wc0 = wn0; wc1 = wn1;
            }

            // --- k2=1: af frags + 16 MFMA
            {
                half8 af[4];
                #pragma unroll
                for (int si = 0; si < 4; ++si)
                    af[si] = *(const half8*)&Tc[p][sw_off((sg * 4 + si) * CB + l15, 4 + quad)];
                #pragma unroll
                for (int si = 0; si < 4; ++si)
                    #pragma unroll
                    for (int ej = 0; ej < 4; ++ej)
                        acc[si][ej] = __builtin_amdgcn_mfma_f32_16x16x32_f16(
                            af[si], bf1[ej], acc[si][ej], 0, 0, 0);
            }
        }

        // --- online softmax accumulate; acc = log2e*feat so exp2(acc) = exp(feat)
        #pragma unroll
        for (int si = 0; si < 4; ++si) {
            const int sl = sg * 4 + si;
            if (sl >= slim) break;    // tail pass: sg=1 contributes nothing
            #pragma unroll
            for (int ej = 0; ej < 4; ++ej) {
                float ie = imgS[sl][e0 + ew * 64 + ej * 16 + l15] * INVK;
                #pragma unroll
                for (int r = 0; r < 4; ++r) {
                    float ev = __builtin_amdgcn_exp2f(acc[si][ej][r]);
                    lacc[ej][r] += ev;
                    aacc[ej][r] += ie * ev;
                }
            }
        }
    }

    // --- combine the two s-groups (stride-33 LDS: bank-conflict-free) and write a/l
    __syncthreads();
    if (sg == 1) {
        const int base = (tid - 256) * 33;
        #pragma unroll
        for (int ej = 0; ej < 4; ++ej)
            #pragma unroll
            for (int r = 0; r < 4; ++r) {
                red[base + ej * 8 + r * 2]     = lacc[ej][r];
                red[base + ej * 8 + r * 2 + 1] = aacc[ej][r];
            }
    }
    __syncthreads();
    if (sg == 0) {
        const int base = tid * 33;
        #pragma unroll
        for (int r = 0; r < 4; ++r) {
            const int cg = c0 + quad * 4 + r;
            if (cg < C) {
                #pragma unroll
                for (int ej = 0; ej < 4; ++ej) {
                    float l = lacc[ej][r] + red[base + ej * 8 + r * 2];
                    float a = aacc[ej][r] + red[base + ej * 8 + r * 2 + 1];
                    const int eg = e0 + ew * 64 + ej * 16 + l15;
                    out[((size_t)b * C + cg) * D + eg] = a / l;
                }
            }
        }
    }
}

} // namespace

extern "C" void kernel_launch(void* const* d_in, const int* in_sizes, int n_in,
                              void* d_out, int out_size, void* d_ws, size_t ws_size,
                              hipStream_t stream) {
    const float* img  = (const float*)d_in[0];
    const float* word = (const float*)d_in[1];
    const float* fw   = (const float*)d_in[2];
    // d_in[3] = fc3_b: constant over softmax axis s -> cancels exactly.
    float* out = (float*)d_out;

    _Float16* W16 = (_Float16*)d_ws;     // 512 KB; only workspace use

    hipLaunchKernelGGL(prep_w16, dim3(128), dim3(256), 0, stream, fw, W16);
    hipLaunchKernelGGL(semdec_mfma, dim3(64, 2, 2), dim3(TPB), 0, stream,
                       img, word, W16, out);
}